// Round 10
// baseline (273.566 us; speedup 1.0000x reference)
//
#include <hip/hip_runtime.h>

// NonlocalWeightedAverage v13: v12 + 4-slot ring, barrier per 2 steps.
// v12 (79 us fused, VGPR 124) proved the conversion hoist; rule learned from
// v11: under waves_per_eu(2) the allocator caps ARCH regs at 128 and spills
// past it -- we have 4 regs of headroom. v13 halves barrier count (17 -> 9)
// via ring depth 4 (slot written at step t is re-read at t+2; one barrier
// after each odd step separates them), keeping v12's strictly-per-step
// staging (8-reg transient). sched_barrier(0) between paired steps prevents
// the scheduler from hoisting the odd step's global loads into the even
// step's MFMA phase (v11's spill mechanism).

#define NPIX 4096
#define ROWB  (528 * 16)       // 8 kchunks * 66 xslots * 16 B = 8448 B
#define SCALE 10.0f
#define XCH   1024             // x floats per channel per block (16 rows * 64)

typedef __attribute__((ext_vector_type(8))) short bf16x8;
typedef __attribute__((ext_vector_type(4))) float f32x4;

#define MF(a, b, c) __builtin_amdgcn_mfma_f32_16x16x32_bf16(a, b, c, 0, 0, 0)

__device__ __forceinline__ float blo(unsigned u) { return __uint_as_float(u << 16); }
__device__ __forceinline__ float bhi(unsigned u) { return __uint_as_float(u & 0xffff0000u); }

// 6 MFMAs into acc[T][KT]: dx outer, ks inner (v4-proven order).
#define MG(T, DBASE, KT) do {                                                 \
    _Pragma("unroll")                                                         \
    for (int dx = 0; dx < 3; ++dx)                                            \
        _Pragma("unroll")                                                     \
        for (int ks = 0; ks < 2; ++ks)                                        \
            acc[T][KT] = MF(AF[((DBASE) + dx) * 2 + ks], B2[ks][dx], acc[T][KT]); \
} while (0)

// myv is LOCAL key row (0..15) within this block's quarter
#define RETIRE(S, myv) do {                                                   \
    _Pragma("unroll")                                                         \
    for (int kt = 0; kt < 4; ++kt) {                                          \
        const int kx = kt * 16 + nl;                                          \
        const float xv0 = xls[(myv) * 64 + kx];                               \
        const float xv1 = xls[XCH + (myv) * 64 + kx];                         \
        const float xv2 = xls[2 * XCH + (myv) * 64 + kx];                     \
        _Pragma("unroll")                                                     \
        for (int rg = 0; rg < 4; ++rg) {                                      \
            const float e = __expf(fmaf(acc[S][kt][rg], SCALE, negM[rg]));    \
            l_[rg] += e;                                                      \
            A0[rg] = fmaf(e, xv0, A0[rg]);                                    \
            A1[rg] = fmaf(e, xv1, A1[rg]);                                    \
            A2[rg] = fmaf(e, xv2, A2[rg]);                                    \
        }                                                                     \
        acc[S][kt] = (f32x4){0.f, 0.f, 0.f, 0.f};                             \
    }                                                                         \
} while (0)

// One step TT (compile-time literal). Feature row g(TT) = R0 - 1 + TT read
// from ring slot TT%4; stage row g(TT+2) = R0+1+TT into slot (TT+2)%4
// (loads issued at step start, ds_write after retire). acc rotation:
// dy=2 -> acc[(TT+2)%3] (row TT-2, retired this step), dy=1 -> acc[TT%3],
// dy=0 -> acc[(TT+1)%3]. No barrier here -- caller places them.
#define STEPX(TT) do {                                                        \
    uint4 Rv0 = (uint4){0u, 0u, 0u, 0u}, Rv1 = (uint4){0u, 0u, 0u, 0u};       \
    if ((TT) <= 15) {                                                         \
        const int g2 = R0 + 1 + (TT);                                         \
        if (g2 < 64) {                                                        \
            Rv0 = fbb[kc0 * NPIX + g2 * 64 + x];                              \
            Rv1 = fbb[kc1 * NPIX + g2 * 64 + x];                              \
        }                                                                     \
    }                                                                         \
    {                                                                         \
        const char* base = ring + ((TT) % 4) * ROWB + bu;                     \
        _Pragma("unroll")                                                     \
        for (int kt = 0; kt < 4; ++kt) {                                      \
            bf16x8 B2[2][3];                                                  \
            _Pragma("unroll")                                                 \
            for (int ks = 0; ks < 2; ++ks) {                                  \
                const char* p = base + (ks * 264 + kt * 16) * 16;             \
                B2[ks][0] = *(const bf16x8*)(p);                              \
                B2[ks][1] = *(const bf16x8*)(p + 16);                         \
                B2[ks][2] = *(const bf16x8*)(p + 32);                         \
            }                                                                 \
            if ((TT) >= 2)                MG(((TT) + 2) % 3, 6, kt);          \
            if ((TT) >= 1 && (TT) <= 16)  MG((TT) % 3,       3, kt);          \
            if ((TT) <= 15)               MG(((TT) + 1) % 3, 0, kt);          \
        }                                                                     \
    }                                                                         \
    if ((TT) >= 2) RETIRE(((TT) + 2) % 3, (TT) - 2);                          \
    if ((TT) <= 15) {                                                         \
        *(uint4*)(ring + (((TT) + 2) % 4) * ROWB + wu0) = Rv0;                \
        *(uint4*)(ring + (((TT) + 2) % 4) * ROWB + wu1) = Rv1;                \
    }                                                                         \
} while (0)

// Paired steps with one barrier. sched_barrier(0) pins the seam so the odd
// step's global loads cannot hoist into the even step (register-liveness
// guard; v11's spill mechanism).
#define S2(TT) do {                                                           \
    STEPX(TT);                                                                \
    __builtin_amdgcn_sched_barrier(0);                                        \
    STEPX((TT) + 1);                                                          \
    if ((TT) < 16) __syncthreads();                                           \
} while (0)

// ---- pre-pass: feature f32 -> bf16 chunks [b*8+c][p=4096][8 ch packed] ----
__global__ __launch_bounds__(256)
void nlwa_convert(const float* __restrict__ feature, uint4* __restrict__ fb)
{
    const int idx = blockIdx.x * 256 + threadIdx.x;   // 4*8*4096 = 131072
    const int p = idx & (NPIX - 1);
    const int cb = idx >> 12;                         // b*8 + c  (0..31)
    const float* src = feature + (size_t)cb * 8 * NPIX + p;
    unsigned h[8];
#pragma unroll
    for (int j = 0; j < 8; ++j) {
        unsigned u = __float_as_uint(src[(size_t)j * NPIX]);
        u = u + 0x7fffu + ((u >> 16) & 1u);           // RNE to bf16
        h[j] = u >> 16;
    }
    fb[idx] = (uint4){h[0] | (h[1] << 16), h[2] | (h[3] << 16),
                      h[4] | (h[5] << 16), h[6] | (h[7] << 16)};
}

__global__ __launch_bounds__(256)
__attribute__((amdgpu_waves_per_eu(2)))
void nlwa_fused(const float* __restrict__ x_lab,
                const uint4* __restrict__ fb16,
                float4* __restrict__ ws)
{
    __shared__ __align__(16) char ring[4 * ROWB];   // 33792 B (4-slot ring)
    __shared__ float xls[3 * XCH];                  // 12288 B
    __shared__ float part[3][4][64];                // 3072 B
    __shared__ float ssq[3][64];                    // 768 B
                                                    // total 49920 B

    const int tid = threadIdx.x;
    const int b = blockIdx.x >> 8;
    const int rem = blockIdx.x & 255;
    const int ny = rem >> 2, kq = rem & 3;
    const int R0 = kq * 16;                         // first key row of quarter
    const int w = tid >> 6, lane = tid & 63;
    const int quad = lane >> 4, nl = lane & 15;
    const int kc0 = 2 * w, kc1 = 2 * w + 1;         // this thread's 2 kchunks
    const int x = lane;
    const int wu0 = (kc0 * 66 + x + 1) * 16;        // ds_write slots
    const int wu1 = (kc1 * 66 + x + 1) * 16;
    const int bu = (quad * 66 + nl) * 16;           // B fragment lane base

    const uint4* fbb = fb16 + (size_t)b * 8 * NPIX; // chunk (c,p) = fbb[c*NPIX+p]
    const float* xb = x_lab + (size_t)b * 3 * NPIX;

    // ---- stage x_lab[b] rows R0..R0+15 (12 KB) into LDS ----
    {
        const int base = R0 * 64;
        float4* d4 = (float4*)xls;
        for (int i = tid; i < 3 * XCH / 4; i += 256) {
            const int ch = i >> 8, off = i & 255;   // 256 float4 per channel
            d4[i] = *(const float4*)(xb + (size_t)ch * NPIX + base + off * 4);
        }
    }
    // ---- zero the pad units of all 4 ring slots ----
    if (tid < 64) {
        const int sl = tid / 16, pu = tid % 16;
        const int u = (pu >> 1) * 66 + (pu & 1) * 65;
        *(uint4*)(ring + sl * ROWB + u * 16) = (uint4){0u, 0u, 0u, 0u};
    }

    // ---- ssq partials for the 3 query rows (from bf16, rounds negM only) ----
#pragma unroll
    for (int dyi = 0; dyi < 3; ++dyi) {
        const int qr = ny + dyi - 1;
        float ss = 0.f;
        if (qr >= 0 && qr < 64) {
            const uint4 v0 = fbb[kc0 * NPIX + qr * 64 + x];
            const uint4 v1 = fbb[kc1 * NPIX + qr * 64 + x];
            const unsigned* pv0 = (const unsigned*)&v0;
            const unsigned* pv1 = (const unsigned*)&v1;
#pragma unroll
            for (int d = 0; d < 4; ++d) {
                float a0 = blo(pv0[d]), a1 = bhi(pv0[d]);
                float b0 = blo(pv1[d]), b1 = bhi(pv1[d]);
                ss = fmaf(a0, a0, ss); ss = fmaf(a1, a1, ss);
                ss = fmaf(b0, b0, ss); ss = fmaf(b1, b1, ss);
            }
        }
        part[dyi][w][x] = ss;
    }

    // ---- A fragments straight from global bf16 (L2-hot), predicated ----
    bf16x8 AF[18];
#pragma unroll
    for (int dyi = 0; dyi < 3; ++dyi) {
        const int qr = ny + dyi - 1;
#pragma unroll
        for (int dx = 0; dx < 3; ++dx) {
            const int cxx = w * 16 + nl + dx - 1;
#pragma unroll
            for (int ks = 0; ks < 2; ++ks) {
                bf16x8 t = (bf16x8){0, 0, 0, 0, 0, 0, 0, 0};
                if (qr >= 0 && qr < 64 && cxx >= 0 && cxx < 64)
                    t = *(const bf16x8*)(fbb + (quad + 4 * ks) * NPIX + qr * 64 + cxx);
                AF[(dyi * 3 + dx) * 2 + ks] = t;
            }
        }
    }

    // ---- stage key rows g(0)=R0-1 -> slot 0, g(1)=R0 -> slot 1 ----
#pragma unroll
    for (int rr = 0; rr < 2; ++rr) {
        const int g = R0 - 1 + rr;
        uint4 v0 = (uint4){0u, 0u, 0u, 0u}, v1 = v0;
        if (g >= 0) {
            v0 = fbb[kc0 * NPIX + g * 64 + x];
            v1 = fbb[kc1 * NPIX + g * 64 + x];
        }
        *(uint4*)(ring + rr * ROWB + wu0) = v0;
        *(uint4*)(ring + rr * ROWB + wu1) = v1;
    }
    __syncthreads();            // part + ring writes visible

    if (tid < 192) {
        const int dyi = tid >> 6, xx = tid & 63;
        float s = 0.f;
#pragma unroll
        for (int k = 0; k < 4; ++k) s += part[dyi][k][xx];
        ssq[dyi][xx] = s;
    }
    __syncthreads();            // ssq ready

    // ---- fixed softmax offsets (query side only; identical across kq) ----
    float negM[4];
#pragma unroll
    for (int rg = 0; rg < 4; ++rg) {
        const int q = w * 16 + quad * 4 + rg;
        float a = 0.f;
#pragma unroll
        for (int dyi = 0; dyi < 3; ++dyi)
#pragma unroll
            for (int dx = -1; dx <= 1; ++dx) {
                const int cx = q + dx;
                a += (cx >= 0 && cx < 64) ? ssq[dyi][cx] : 0.f;
            }
        negM[rg] = -SCALE * a;
    }

    float l_[4], A0[4], A1[4], A2[4];
#pragma unroll
    for (int rg = 0; rg < 4; ++rg) { l_[rg] = 0.f; A0[rg] = 0.f; A1[rg] = 0.f; A2[rg] = 0.f; }
    f32x4 acc[3][4];
#pragma unroll
    for (int i = 0; i < 3; ++i)
#pragma unroll
        for (int kt = 0; kt < 4; ++kt)
            acc[i][kt] = (f32x4){0.f, 0.f, 0.f, 0.f};

    // ---- 18 steps, one barrier per 2 steps (9 barriers incl. none at end) ----
    S2(0);  S2(2);  S2(4);  S2(6);  S2(8);
    S2(10); S2(12); S2(14); S2(16);

    // ---- combine: shfl-reduce the 16 key cols within each quad group ----
#pragma unroll
    for (int rg = 0; rg < 4; ++rg) {
#pragma unroll
        for (int off = 8; off >= 1; off >>= 1) {
            l_[rg] += __shfl_down(l_[rg], off, 16);
            A0[rg] += __shfl_down(A0[rg], off, 16);
            A1[rg] += __shfl_down(A1[rg], off, 16);
            A2[rg] += __shfl_down(A2[rg], off, 16);
        }
    }
    if (nl == 0) {
#pragma unroll
        for (int rg = 0; rg < 4; ++rg) {
            const int q = w * 16 + quad * 4 + rg;
            ws[(size_t)blockIdx.x * 64 + q] =
                make_float4(l_[rg], A0[rg], A1[rg], A2[rg]);
        }
    }
}

// Combine the four key-quarter partials and normalize. 4*64*64 = 16384 queries.
__global__ __launch_bounds__(256)
void nlwa_combine(const float4* __restrict__ ws, float* __restrict__ out)
{
    const int i = blockIdx.x * 256 + threadIdx.x;
    const int b = i >> 12, ny = (i >> 6) & 63, q = i & 63;
    const size_t base = ((size_t)(b * 64 + ny) * 4) * 64 + q;
    float4 s = make_float4(0.f, 0.f, 0.f, 0.f);
#pragma unroll
    for (int kq = 0; kq < 4; ++kq) {
        const float4 p = ws[base + (size_t)kq * 64];
        s.x += p.x; s.y += p.y; s.z += p.z; s.w += p.w;
    }
    const float inv = 1.0f / s.x;
    float* o = out + (size_t)b * 3 * NPIX + ny * 64 + q;
    o[0]        = s.y * inv;
    o[NPIX]     = s.z * inv;
    o[2 * NPIX] = s.w * inv;
}

extern "C" void kernel_launch(void* const* d_in, const int* in_sizes, int n_in,
                              void* d_out, int out_size, void* d_ws, size_t ws_size,
                              hipStream_t stream) {
    (void)in_sizes; (void)n_in; (void)out_size; (void)ws_size;
    const float* x_lab   = (const float*)d_in[0];
    const float* feature = (const float*)d_in[1];
    float* out = (float*)d_out;
    float4* wsp = (float4*)d_ws;                     // partials: 1024*64*16 B = 1 MB
    uint4* fb   = (uint4*)((char*)d_ws + (1 << 20)); // bf16 feature: 2 MB
    nlwa_convert<<<dim3(512), dim3(256), 0, stream>>>(feature, fb);
    nlwa_fused<<<dim3(1024), dim3(256), 0, stream>>>(x_lab, fb, wsp);
    nlwa_combine<<<dim3(64), dim3(256), 0, stream>>>(wsp, out);
}

// Round 11
// 125.707 us; speedup vs baseline: 2.1762x; 2.1762x over previous
//
#include <hip/hip_runtime.h>

// NonlocalWeightedAverage v14: halve the key split (quarters -> halves) to
// amortize per-block overhead; loop body is v12's proven STEP unchanged.
// v13 post-mortem: pairing 2 unrolled steps per barrier needs >128 arch regs
// -> spill (3rd confirmation of the 128-arch cap under waves_per_eu(2)).
// v12 overhead shape: 1024 blocks x 18 steps, each block pays a prologue
// (x stage, ssq, 18 AF global loads, negM) that is IDENTICAL across the 4
// key-quarter blocks of one (b,ny). v14: 512 blocks x 34 steps -- prologues
// per CU 4->2, step-epochs 72->68, combine partials 4->2, AF loads halved.
// LDS 53,760 B (x2 = 107.5 KB <= 160) keeps 2 blocks/CU. Regs: same STEP,
// same 8-reg staging transient -> ~124 arch (alarm: 128 + WRITE_SIZE spike).

#define NPIX 4096
#define ROWB  (528 * 16)       // 8 kchunks * 66 xslots * 16 B = 8448 B
#define SCALE 10.0f
#define XCH   2048             // x floats per channel per block (32 rows * 64)

typedef __attribute__((ext_vector_type(8))) short bf16x8;
typedef __attribute__((ext_vector_type(4))) float f32x4;

#define MF(a, b, c) __builtin_amdgcn_mfma_f32_16x16x32_bf16(a, b, c, 0, 0, 0)

__device__ __forceinline__ float blo(unsigned u) { return __uint_as_float(u << 16); }
__device__ __forceinline__ float bhi(unsigned u) { return __uint_as_float(u & 0xffff0000u); }

// 6 MFMAs into acc[T][KT]: dx outer, ks inner (v4-proven order).
#define MG(T, DBASE, KT) do {                                                 \
    _Pragma("unroll")                                                         \
    for (int dx = 0; dx < 3; ++dx)                                            \
        _Pragma("unroll")                                                     \
        for (int ks = 0; ks < 2; ++ks)                                        \
            acc[T][KT] = MF(AF[((DBASE) + dx) * 2 + ks], B2[ks][dx], acc[T][KT]); \
} while (0)

// myv is LOCAL key row (0..31) within this block's half
#define RETIRE(S, myv) do {                                                   \
    _Pragma("unroll")                                                         \
    for (int kt = 0; kt < 4; ++kt) {                                          \
        const int kx = kt * 16 + nl;                                          \
        const float xv0 = xls[(myv) * 64 + kx];                               \
        const float xv1 = xls[XCH + (myv) * 64 + kx];                         \
        const float xv2 = xls[2 * XCH + (myv) * 64 + kx];                     \
        _Pragma("unroll")                                                     \
        for (int rg = 0; rg < 4; ++rg) {                                      \
            const float e = __expf(fmaf(acc[S][kt][rg], SCALE, negM[rg]));    \
            l_[rg] += e;                                                      \
            A0[rg] = fmaf(e, xv0, A0[rg]);                                    \
            A1[rg] = fmaf(e, xv1, A1[rg]);                                    \
            A2[rg] = fmaf(e, xv2, A2[rg]);                                    \
        }                                                                     \
        acc[S][kt] = (f32x4){0.f, 0.f, 0.f, 0.f};                             \
    }                                                                         \
} while (0)

// Step t processes feature row g(t) = R0 - 1 + t, t = 0..33 (32 rows + halo);
// the rb-loop runs t to 35 with all guards false at 34,35. Staging: issue 2
// dwordx4 loads of row g(t+2) at step START (latency hides under the MFMAs);
// ds_write into ring slot SR AFTER retire; barrier. 3-slot ring: slot SR was
// last read (as RM) at step t-1, barrier-separated; next read at t+2.
#define STEP(RM, SN, SR, tt) do {                                             \
    const int t_ = (tt);                                                      \
    uint4 Rv0 = (uint4){0u, 0u, 0u, 0u}, Rv1 = (uint4){0u, 0u, 0u, 0u};       \
    if (t_ <= 31) {                                                           \
        const int g2 = R0 + 1 + t_;                                           \
        if (g2 < 64) {                                                        \
            Rv0 = fbb[kc0 * NPIX + g2 * 64 + x];                              \
            Rv1 = fbb[kc1 * NPIX + g2 * 64 + x];                              \
        }                                                                     \
    }                                                                         \
    if (t_ <= 33) {                                                           \
        const char* base = ring + (RM) * ROWB + bu;                           \
        _Pragma("unroll")                                                     \
        for (int kt = 0; kt < 4; ++kt) {                                      \
            bf16x8 B2[2][3];                                                  \
            _Pragma("unroll")                                                 \
            for (int ks = 0; ks < 2; ++ks) {                                  \
                const char* p = base + (ks * 264 + kt * 16) * 16;             \
                B2[ks][0] = *(const bf16x8*)(p);                              \
                B2[ks][1] = *(const bf16x8*)(p + 16);                         \
                B2[ks][2] = *(const bf16x8*)(p + 32);                         \
            }                                                                 \
            if (t_ >= 2)              MG(((SR)), 6, kt);   /* my=g-1, dy=2 */ \
            if (t_ >= 1 && t_ <= 32)  MG(((RM)), 3, kt);   /* my=g,   dy=1 */ \
            if (t_ <= 31)             MG(((SN)), 0, kt);   /* my=g+1, dy=0 */ \
        }                                                                     \
    }                                                                         \
    if (t_ >= 2 && t_ <= 33) RETIRE(SR, t_ - 2);                              \
    if (t_ <= 31) {                                                           \
        *(uint4*)(ring + (SR) * ROWB + wu0) = Rv0;                            \
        *(uint4*)(ring + (SR) * ROWB + wu1) = Rv1;                            \
    }                                                                         \
    if (t_ < 33) __syncthreads();                                             \
} while (0)

// ---- pre-pass: feature f32 -> bf16 chunks [b*8+c][p=4096][8 ch packed] ----
__global__ __launch_bounds__(256)
void nlwa_convert(const float* __restrict__ feature, uint4* __restrict__ fb)
{
    const int idx = blockIdx.x * 256 + threadIdx.x;   // 4*8*4096 = 131072
    const int p = idx & (NPIX - 1);
    const int cb = idx >> 12;                         // b*8 + c  (0..31)
    const float* src = feature + (size_t)cb * 8 * NPIX + p;
    unsigned h[8];
#pragma unroll
    for (int j = 0; j < 8; ++j) {
        unsigned u = __float_as_uint(src[(size_t)j * NPIX]);
        u = u + 0x7fffu + ((u >> 16) & 1u);           // RNE to bf16
        h[j] = u >> 16;
    }
    fb[idx] = (uint4){h[0] | (h[1] << 16), h[2] | (h[3] << 16),
                      h[4] | (h[5] << 16), h[6] | (h[7] << 16)};
}

__global__ __launch_bounds__(256)
__attribute__((amdgpu_waves_per_eu(2)))
void nlwa_fused(const float* __restrict__ x_lab,
                const uint4* __restrict__ fb16,
                float4* __restrict__ ws)
{
    __shared__ __align__(16) char ring[3 * ROWB];   // 25344 B
    __shared__ float xls[3 * XCH];                  // 24576 B
    __shared__ float part[3][4][64];                // 3072 B
    __shared__ float ssq[3][64];                    // 768 B
                                                    // total 53760 B -> 2 blk/CU

    const int tid = threadIdx.x;
    const int b = blockIdx.x >> 7;
    const int rem = blockIdx.x & 127;
    const int ny = rem >> 1, half = rem & 1;
    const int R0 = half * 32;                       // first key row of half
    const int w = tid >> 6, lane = tid & 63;
    const int quad = lane >> 4, nl = lane & 15;
    const int kc0 = 2 * w, kc1 = 2 * w + 1;         // this thread's 2 kchunks
    const int x = lane;
    const int wu0 = (kc0 * 66 + x + 1) * 16;        // ds_write slots
    const int wu1 = (kc1 * 66 + x + 1) * 16;
    const int bu = (quad * 66 + nl) * 16;           // B fragment lane base

    const uint4* fbb = fb16 + (size_t)b * 8 * NPIX; // chunk (c,p) = fbb[c*NPIX+p]
    const float* xb = x_lab + (size_t)b * 3 * NPIX;

    // ---- stage x_lab[b] rows R0..R0+31 (24 KB) into LDS ----
    {
        const int base = R0 * 64;
        float4* d4 = (float4*)xls;
        for (int i = tid; i < 3 * XCH / 4; i += 256) {
            const int ch = i >> 9, off = i & 511;   // 512 float4 per channel
            d4[i] = *(const float4*)(xb + (size_t)ch * NPIX + base + off * 4);
        }
    }
    // ---- zero the pad units of all 3 ring slots ----
    if (tid < 48) {
        const int sl = tid / 16, pu = tid % 16;
        const int u = (pu >> 1) * 66 + (pu & 1) * 65;
        *(uint4*)(ring + sl * ROWB + u * 16) = (uint4){0u, 0u, 0u, 0u};
    }

    // ---- ssq partials for the 3 query rows (from bf16, rounds negM only) ----
#pragma unroll
    for (int dyi = 0; dyi < 3; ++dyi) {
        const int qr = ny + dyi - 1;
        float ss = 0.f;
        if (qr >= 0 && qr < 64) {
            const uint4 v0 = fbb[kc0 * NPIX + qr * 64 + x];
            const uint4 v1 = fbb[kc1 * NPIX + qr * 64 + x];
            const unsigned* pv0 = (const unsigned*)&v0;
            const unsigned* pv1 = (const unsigned*)&v1;
#pragma unroll
            for (int d = 0; d < 4; ++d) {
                float a0 = blo(pv0[d]), a1 = bhi(pv0[d]);
                float b0 = blo(pv1[d]), b1 = bhi(pv1[d]);
                ss = fmaf(a0, a0, ss); ss = fmaf(a1, a1, ss);
                ss = fmaf(b0, b0, ss); ss = fmaf(b1, b1, ss);
            }
        }
        part[dyi][w][x] = ss;
    }

    // ---- A fragments straight from global bf16 (L2-hot), predicated ----
    bf16x8 AF[18];
#pragma unroll
    for (int dyi = 0; dyi < 3; ++dyi) {
        const int qr = ny + dyi - 1;
#pragma unroll
        for (int dx = 0; dx < 3; ++dx) {
            const int cxx = w * 16 + nl + dx - 1;
#pragma unroll
            for (int ks = 0; ks < 2; ++ks) {
                bf16x8 t = (bf16x8){0, 0, 0, 0, 0, 0, 0, 0};
                if (qr >= 0 && qr < 64 && cxx >= 0 && cxx < 64)
                    t = *(const bf16x8*)(fbb + (quad + 4 * ks) * NPIX + qr * 64 + cxx);
                AF[(dyi * 3 + dx) * 2 + ks] = t;
            }
        }
    }

    // ---- stage key rows g(0)=R0-1 -> slot 0, g(1)=R0 -> slot 1 ----
#pragma unroll
    for (int rr = 0; rr < 2; ++rr) {
        const int g = R0 - 1 + rr;
        uint4 v0 = (uint4){0u, 0u, 0u, 0u}, v1 = v0;
        if (g >= 0) {
            v0 = fbb[kc0 * NPIX + g * 64 + x];
            v1 = fbb[kc1 * NPIX + g * 64 + x];
        }
        *(uint4*)(ring + rr * ROWB + wu0) = v0;
        *(uint4*)(ring + rr * ROWB + wu1) = v1;
    }
    __syncthreads();            // part + ring writes visible

    if (tid < 192) {
        const int dyi = tid >> 6, xx = tid & 63;
        float s = 0.f;
#pragma unroll
        for (int k = 0; k < 4; ++k) s += part[dyi][k][xx];
        ssq[dyi][xx] = s;
    }
    __syncthreads();            // ssq ready

    // ---- fixed softmax offsets (query side only; identical across halves) ----
    float negM[4];
#pragma unroll
    for (int rg = 0; rg < 4; ++rg) {
        const int q = w * 16 + quad * 4 + rg;
        float a = 0.f;
#pragma unroll
        for (int dyi = 0; dyi < 3; ++dyi)
#pragma unroll
            for (int dx = -1; dx <= 1; ++dx) {
                const int cx = q + dx;
                a += (cx >= 0 && cx < 64) ? ssq[dyi][cx] : 0.f;
            }
        negM[rg] = -SCALE * a;
    }

    float l_[4], A0[4], A1[4], A2[4];
#pragma unroll
    for (int rg = 0; rg < 4; ++rg) { l_[rg] = 0.f; A0[rg] = 0.f; A1[rg] = 0.f; A2[rg] = 0.f; }
    f32x4 acc[3][4];
#pragma unroll
    for (int i = 0; i < 3; ++i)
#pragma unroll
        for (int kt = 0; kt < 4; ++kt)
            acc[i][kt] = (f32x4){0.f, 0.f, 0.f, 0.f};

    // ---- 34 active steps (t=0..33; t=34,35 are guard-false no-ops) ----
    for (int rb = 0; rb < 36; rb += 3) {
        STEP(0, 1, 2, rb);
        STEP(1, 2, 0, rb + 1);
        STEP(2, 0, 1, rb + 2);
    }

    // ---- combine: shfl-reduce the 16 key cols within each quad group ----
#pragma unroll
    for (int rg = 0; rg < 4; ++rg) {
#pragma unroll
        for (int off = 8; off >= 1; off >>= 1) {
            l_[rg] += __shfl_down(l_[rg], off, 16);
            A0[rg] += __shfl_down(A0[rg], off, 16);
            A1[rg] += __shfl_down(A1[rg], off, 16);
            A2[rg] += __shfl_down(A2[rg], off, 16);
        }
    }
    if (nl == 0) {
#pragma unroll
        for (int rg = 0; rg < 4; ++rg) {
            const int q = w * 16 + quad * 4 + rg;
            ws[(size_t)blockIdx.x * 64 + q] =
                make_float4(l_[rg], A0[rg], A1[rg], A2[rg]);
        }
    }
}

// Combine the two key-half partials and normalize. 4*64*64 = 16384 queries.
__global__ __launch_bounds__(256)
void nlwa_combine(const float4* __restrict__ ws, float* __restrict__ out)
{
    const int i = blockIdx.x * 256 + threadIdx.x;
    const int b = i >> 12, ny = (i >> 6) & 63, q = i & 63;
    const size_t base = ((size_t)(b * 64 + ny) * 2) * 64 + q;
    const float4 p0 = ws[base];
    const float4 p1 = ws[base + 64];
    const float inv = 1.0f / (p0.x + p1.x);
    float* o = out + (size_t)b * 3 * NPIX + ny * 64 + q;
    o[0]        = (p0.y + p1.y) * inv;
    o[NPIX]     = (p0.z + p1.z) * inv;
    o[2 * NPIX] = (p0.w + p1.w) * inv;
}

extern "C" void kernel_launch(void* const* d_in, const int* in_sizes, int n_in,
                              void* d_out, int out_size, void* d_ws, size_t ws_size,
                              hipStream_t stream) {
    (void)in_sizes; (void)n_in; (void)out_size; (void)ws_size;
    const float* x_lab   = (const float*)d_in[0];
    const float* feature = (const float*)d_in[1];
    float* out = (float*)d_out;
    float4* wsp = (float4*)d_ws;                     // partials: 512*64*16 B = 512 KB
    uint4* fb   = (uint4*)((char*)d_ws + (1 << 20)); // bf16 feature: 2 MB
    nlwa_convert<<<dim3(512), dim3(256), 0, stream>>>(feature, fb);
    nlwa_fused<<<dim3(512), dim3(256), 0, stream>>>(x_lab, fb, wsp);
    nlwa_combine<<<dim3(64), dim3(256), 0, stream>>>(wsp, out);
}